// Round 4
// baseline (144.887 us; speedup 1.0000x reference)
//
#include <hip/hip_runtime.h>
#include <math.h>

// Problem constants (from reference)
constexpr int NODE_NUM = 1000000;
constexpr int TYPE_NUM = 4;
constexpr int DIM      = 128;
constexpr int K        = 5;
constexpr int M        = 5;
constexpr int B        = 256;
constexpr int LK       = 75;          // L - K
constexpr int NBL      = B * LK;      // 19200 (b,l) pairs
constexpr int PS       = NBL * K;     // 96000  pos_score elems
constexpr int NS       = NBL * K * M; // 480000 neg_score elems

// Output layout (concatenated flat, all float32):
// [0,        PS)            : pos_score
// [PS,       PS+NS)         : neg_score
// [PS+NS,    PS+NS+PS)      : pos_pair_type_out (as float)
// [PS+NS+PS, PS+NS+PS+NS)   : neg_pair_type_out (as float)

// Row r in [0,30): r<5 -> pos sample r, else neg sample r-5.
// Pair j covers rows {2j,2j+1}: lanes 0-31 take row 2j, lanes 32-63 row 2j+1
// -> each gather instruction moves 1 KB (16 B x 64 lanes), 15+1 gathers/wave.
// walk_type is wave-uniform -> only 4 of 16 relationship rows are reachable:
// precompute sigmoid fragments for those 4 types in registers (no LDS, no barrier).

__global__ __launch_bounds__(256) void skipgram_kernel(
    const int*   __restrict__ walk,       // [NBL]
    const int*   __restrict__ pos,        // [NBL*K]
    const int*   __restrict__ neg,        // [NBL*K*M]
    const int*   __restrict__ walk_type,  // [NBL]
    const int*   __restrict__ pos_type,   // [NBL*K]
    const int*   __restrict__ neg_type,   // [NBL*K*M]
    const float* __restrict__ node_emb,   // [NODE_NUM*DIM]
    const float* __restrict__ rel_emb,    // [16*DIM]
    float*       __restrict__ out)
{
    const int tid  = threadIdx.x;
    const int wave = tid >> 6;
    const int lane = tid & 63;
    const int half = lane >> 5;   // 0: even row of pair, 1: odd row
    const int hl   = lane & 31;   // this lane's dims: 4*hl .. 4*hl+3

    int idx = blockIdx.x * 4 + wave;                 // b*LK + l (wave-uniform)
    idx = __builtin_amdgcn_readfirstlane(idx);       // force scalar index path

    const int wnode = walk[idx];
    const int wt    = walk_type[idx];

    // Row node-ids and sample-types for all 30 rows (uniform -> scalar loads)
    int idxs[30], st[30];
    #pragma unroll
    for (int r = 0; r < 30; ++r) {
        if (r < K) {
            idxs[r] = pos[idx * K + r];
            st[r]   = pos_type[idx * K + r];
        } else {
            idxs[r] = neg[idx * K * M + r - K];
            st[r]   = neg_type[idx * K * M + r - K];
        }
    }

    // Issue walk-row + all 15 paired sample gathers up front (max loads in flight)
    const float4 we = *(const float4*)(node_emb + (size_t)wnode * DIM + 4 * hl);
    float4 ev[15];
    #pragma unroll
    for (int j = 0; j < 15; ++j) {
        const int myid = half ? idxs[2 * j + 1] : idxs[2 * j];
        ev[j] = *(const float4*)(node_emb + (size_t)myid * DIM + 4 * hl);
    }

    // Sigmoid fragments for the 4 reachable relationship rows (type t = sample type)
    // rel row = 4*wt + t; 8 KB table is L1-resident after the first blocks.
    float4 sgt[4];
    #pragma unroll
    for (int t = 0; t < 4; ++t) {
        const float4 x = *(const float4*)(rel_emb + (size_t)(TYPE_NUM * wt + t) * DIM + 4 * hl);
        sgt[t].x = 1.0f / (1.0f + __expf(-x.x));
        sgt[t].y = 1.0f / (1.0f + __expf(-x.y));
        sgt[t].z = 1.0f / (1.0f + __expf(-x.z));
        sgt[t].w = 1.0f / (1.0f + __expf(-x.w));
    }

    // Pre-gate the walk fragment per type: wg[t] = we * sgt[t]  (4x float4 = 16 regs)
    float4 wg[4];
    #pragma unroll
    for (int t = 0; t < 4; ++t) {
        wg[t].x = we.x * sgt[t].x; wg[t].y = we.y * sgt[t].y;
        wg[t].z = we.z * sgt[t].z; wg[t].w = we.w * sgt[t].w;
    }

    // Compute, reduce, store per pair
    #pragma unroll
    for (int j = 0; j < 15; ++j) {
        const int myst = half ? st[2 * j + 1] : st[2 * j];   // per-lane 0..3
        // select wg[myst] via cndmask chain (no dynamic register indexing)
        const bool lo = (myst & 1), hi = (myst & 2);
        float4 a, b, g;
        a.x = lo ? wg[1].x : wg[0].x; a.y = lo ? wg[1].y : wg[0].y;
        a.z = lo ? wg[1].z : wg[0].z; a.w = lo ? wg[1].w : wg[0].w;
        b.x = lo ? wg[3].x : wg[2].x; b.y = lo ? wg[3].y : wg[2].y;
        b.z = lo ? wg[3].z : wg[2].z; b.w = lo ? wg[3].w : wg[2].w;
        g.x = hi ? b.x : a.x; g.y = hi ? b.y : a.y;
        g.z = hi ? b.z : a.z; g.w = hi ? b.w : a.w;

        float v = g.x * ev[j].x + g.y * ev[j].y + g.z * ev[j].z + g.w * ev[j].w;
        #pragma unroll
        for (int m2 = 16; m2 >= 1; m2 >>= 1) v += __shfl_xor(v, m2, 64);

        const int r    = 2 * j + half;
        const int mytp = TYPE_NUM * wt + myst;
        if (hl == 0) {
            if (r < K) {
                out[idx * K + r]           = v;
                out[PS + NS + idx * K + r] = (float)(TYPE_NUM * TYPE_NUM * r + mytp);
            } else {
                const int rr = r - K;          // 0..24
                const int k  = rr / M;         // compile-time per (j,half)
                out[PS + idx * K * M + rr]           = v;
                out[PS + NS + PS + idx * K * M + rr] = (float)(TYPE_NUM * TYPE_NUM * k + mytp);
            }
        }
    }
}

extern "C" void kernel_launch(void* const* d_in, const int* in_sizes, int n_in,
                              void* d_out, int out_size, void* d_ws, size_t ws_size,
                              hipStream_t stream) {
    const int*   walk      = (const int*)d_in[0];
    const int*   pos       = (const int*)d_in[1];
    const int*   neg       = (const int*)d_in[2];
    const int*   walk_type = (const int*)d_in[3];
    const int*   pos_type  = (const int*)d_in[4];
    const int*   neg_type  = (const int*)d_in[5];
    const float* node_emb  = (const float*)d_in[6];
    const float* rel_emb   = (const float*)d_in[7];
    float* out = (float*)d_out;

    const int blocks = NBL / 4;  // 4 waves per block, one (b,l) per wave
    skipgram_kernel<<<blocks, 256, 0, stream>>>(
        walk, pos, neg, walk_type, pos_type, neg_type, node_emb, rel_emb, out);
}

// Round 5
// 53.822 us; speedup vs baseline: 2.6920x; 2.6920x over previous
//
#include <hip/hip_runtime.h>
#include <math.h>

// Problem constants (from reference)
constexpr int NODE_NUM = 1000000;
constexpr int TYPE_NUM = 4;
constexpr int DIM      = 128;
constexpr int K        = 5;
constexpr int M        = 5;
constexpr int B        = 256;
constexpr int LK       = 75;          // L - K
constexpr int NBL      = B * LK;      // 19200 (b,l) pairs
constexpr int PS       = NBL * K;     // 96000  pos_score elems
constexpr int NS       = NBL * K * M; // 480000 neg_score elems

constexpr int WPB = 8;                // waves per block

// Output layout (concatenated flat, all float32):
// [0,        PS)            : pos_score
// [PS,       PS+NS)         : neg_score
// [PS+NS,    PS+NS+PS)      : pos_pair_type_out (as float)
// [PS+NS+PS, PS+NS+PS+NS)   : neg_pair_type_out (as float)

// R2 structure (best: 54.4 us): pair j covers rows {2j,2j+1}; lanes 0-31 take
// row 2j, lanes 32-63 row 2j+1 -> 1 KB per gather instruction; all 15 gathers
// issued up front. Tweaks vs R2: 8 waves/block (halves total sigmoid staging
// work) and __expf. NO extra register-resident tables (R4's spill lesson).

__global__ __launch_bounds__(WPB * 64) void skipgram_kernel(
    const int*   __restrict__ walk,       // [NBL]
    const int*   __restrict__ pos,        // [NBL*K]
    const int*   __restrict__ neg,        // [NBL*K*M]
    const int*   __restrict__ walk_type,  // [NBL]
    const int*   __restrict__ pos_type,   // [NBL*K]
    const int*   __restrict__ neg_type,   // [NBL*K*M]
    const float* __restrict__ node_emb,   // [NODE_NUM*DIM]
    const float* __restrict__ rel_emb,    // [16*DIM]
    float*       __restrict__ out)
{
    // Stage sigmoid(relationship_embedding) in LDS: 16*128 floats = 8 KB
    __shared__ float sig[TYPE_NUM * TYPE_NUM * DIM];
    const int tid = threadIdx.x;
    for (int i = tid; i < TYPE_NUM * TYPE_NUM * DIM; i += WPB * 64) {
        const float x = rel_emb[i];
        sig[i] = 1.0f / (1.0f + __expf(-x));
    }
    __syncthreads();

    const int wave = tid >> 6;
    const int lane = tid & 63;
    const int half = lane >> 5;   // 0: even row of pair, 1: odd row
    const int hl   = lane & 31;   // position within 32-lane half (dims 4*hl..4*hl+3)

    int idx = blockIdx.x * WPB + wave;               // b*LK + l  (wave-uniform)
    idx = __builtin_amdgcn_readfirstlane(idx);       // force scalar → s_load for indices

    const int wnode = walk[idx];
    const int wt    = walk_type[idx];

    // walk embedding fragment: both halves load the same 16B (HW coalesces)
    const float4 we = *(const float4*)(node_emb + (size_t)wnode * DIM + 4 * hl);

    // Types for all 30 rows (scalar loads, kept for gate lookup + type output)
    int tpA[15], tpB[15];
    #pragma unroll
    for (int j = 0; j < 15; ++j) {
        const int r0 = 2 * j, r1 = 2 * j + 1;
        tpA[j] = (r0 < K) ? pos_type[idx * K + r0] : neg_type[idx * K * M + r0 - K];
        tpB[j] = (r1 < K) ? pos_type[idx * K + r1] : neg_type[idx * K * M + r1 - K];
    }

    // Issue all 15 paired gathers up-front (1 KB per instruction per wave)
    float4 ev[15];
    #pragma unroll
    for (int j = 0; j < 15; ++j) {
        const int r0 = 2 * j, r1 = 2 * j + 1;
        const int i0 = (r0 < K) ? pos[idx * K + r0] : neg[idx * K * M + r0 - K];
        const int i1 = (r1 < K) ? pos[idx * K + r1] : neg[idx * K * M + r1 - K];
        const int myid = half ? i1 : i0;
        ev[j] = *(const float4*)(node_emb + (size_t)myid * DIM + 4 * hl);
    }

    // Partial dot per row: walk_e * sigmoid(rel) * sample_e over this lane's 4 dims
    float p[15];
    #pragma unroll
    for (int j = 0; j < 15; ++j) {
        const int mypt = half ? tpB[j] : tpA[j];
        const float4 sg = *(const float4*)(&sig[(TYPE_NUM * wt + mypt) * DIM + 4 * hl]);
        p[j] = we.x * sg.x * ev[j].x + we.y * sg.y * ev[j].y
             + we.z * sg.z * ev[j].z + we.w * sg.w * ev[j].w;
    }

    // Butterfly reduce within each 32-lane half (both rows of a pair at once)
    #pragma unroll
    for (int j = 0; j < 15; ++j) {
        float v = p[j];
        #pragma unroll
        for (int m2 = 16; m2 >= 1; m2 >>= 1) v += __shfl_xor(v, m2, 64);
        p[j] = v;
    }

    // Stores: lane hl==0 of each half writes its row's score + pair-type code
    #pragma unroll
    for (int j = 0; j < 15; ++j) {
        const int r    = 2 * j + half;
        const int mytp = half ? tpB[j] : tpA[j];
        if (hl == 0) {
            if (r < K) {
                out[idx * K + r]           = p[j];
                out[PS + NS + idx * K + r] = (float)(TYPE_NUM * TYPE_NUM * r + TYPE_NUM * wt + mytp);
            } else {
                const int rr = r - K;            // 0..24
                const int k  = rr / M;           // window offset (compile-time per j,half)
                out[PS + idx * K * M + rr]           = p[j];
                out[PS + NS + PS + idx * K * M + rr] = (float)(TYPE_NUM * TYPE_NUM * k + TYPE_NUM * wt + mytp);
            }
        }
    }
}

extern "C" void kernel_launch(void* const* d_in, const int* in_sizes, int n_in,
                              void* d_out, int out_size, void* d_ws, size_t ws_size,
                              hipStream_t stream) {
    const int*   walk      = (const int*)d_in[0];
    const int*   pos       = (const int*)d_in[1];
    const int*   neg       = (const int*)d_in[2];
    const int*   walk_type = (const int*)d_in[3];
    const int*   pos_type  = (const int*)d_in[4];
    const int*   neg_type  = (const int*)d_in[5];
    const float* node_emb  = (const float*)d_in[6];
    const float* rel_emb   = (const float*)d_in[7];
    float* out = (float*)d_out;

    const int blocks = NBL / WPB;  // 8 waves per block, one (b,l) per wave
    skipgram_kernel<<<blocks, WPB * 64, 0, stream>>>(
        walk, pos, neg, walk_type, pos_type, neg_type, node_emb, rel_emb, out);
}